// Round 3
// baseline (1068.071 us; speedup 1.0000x reference)
//
#include <hip/hip_runtime.h>
#include <hip/hip_bf16.h>

#define NNODES 50000
#define NEDGES 800000
#define ETOT   (NNODES + NEDGES)

typedef __attribute__((ext_vector_type(8))) short short8;
typedef __attribute__((ext_vector_type(4))) float floatx4;

__device__ __forceinline__ float bf2f(__hip_bfloat16 x) { return __bfloat162float(x); }
__device__ __forceinline__ __hip_bfloat16 f2bf(float f) { return __float2bfloat16(f); }
// NaN->0, clamp to +-c. For correct fp32 data the clamps never bind.
__device__ __forceinline__ float sane(float v, float c) {
  v = (v == v) ? v : 0.f;
  return fminf(fmaxf(v, -c), c);
}

// ---------------- utility fills ----------------
__global__ void zero_int_kernel(int* __restrict__ p, int n) {
  int i = blockIdx.x * blockDim.x + threadIdx.x;
  if (i < n) p[i] = 0;
}
__global__ void fill_out_kernel(float* __restrict__ o, int n, float v) {
  int i = blockIdx.x * blockDim.x + threadIdx.x;
  if (i < n) o[i] = v;
}
// fp32 -> split bf16 (hi, lo), sanitized
__global__ void split_input_kernel(const float* __restrict__ in,
                                   __hip_bfloat16* __restrict__ hi,
                                   __hip_bfloat16* __restrict__ lo, int n) {
  int i = blockIdx.x * blockDim.x + threadIdx.x;
  if (i >= n) return;
  float v = sane(in[i], 1e4f);
  __hip_bfloat16 h = f2bf(v);
  hi[i] = h;
  lo[i] = f2bf(v - bf2f(h));
}

// ---------------- CSR build (dst-sorted) ----------------
__global__ void degree_kernel(const int* __restrict__ ei, int* __restrict__ deg) {
  int p = blockIdx.x * blockDim.x + threadIdx.x;
  if (p >= ETOT) return;
  int dst = (p < NEDGES) ? ei[NEDGES + p] : (p - NEDGES);
  dst = min(max(dst, 0), NNODES - 1);
  atomicAdd(&deg[dst], 1);
}

__global__ __launch_bounds__(256) void scan_kernel(const int* __restrict__ deg,
                                                   int* __restrict__ row_ptr,
                                                   int* __restrict__ cursor) {
  __shared__ int sh[256];
  int t = threadIdx.x;
  const int n = NNODES;
  const int chunk = (n + 255) / 256;
  int beg = min(n, t * chunk);
  int end = min(n, beg + chunk);
  int s = 0;
  for (int i = beg; i < end; ++i) s += deg[i];
  sh[t] = s;
  __syncthreads();
  for (int off = 1; off < 256; off <<= 1) {
    int v = (t >= off) ? sh[t - off] : 0;
    __syncthreads();
    sh[t] += v;
    __syncthreads();
  }
  int run = sh[t] - s;  // exclusive prefix
  for (int i = beg; i < end; ++i) {
    int d = deg[i];
    row_ptr[i] = run;
    cursor[i] = run;
    run += d;
  }
  if (t == 255) row_ptr[n] = sh[255];
}

__global__ void scatter_kernel(const int* __restrict__ ei, int* __restrict__ cursor,
                               int* __restrict__ csr_src) {
  int p = blockIdx.x * blockDim.x + threadIdx.x;
  if (p >= ETOT) return;
  int src, dst;
  if (p < NEDGES) { src = ei[p]; dst = ei[NEDGES + p]; }
  else            { src = p - NEDGES; dst = src; }
  src = min(max(src, 0), NNODES - 1);
  dst = min(max(dst, 0), NNODES - 1);
  int pos = atomicAdd(&cursor[dst], 1);
  pos = min(max(pos, 0), ETOT - 1);
  csr_src[pos] = src;
}

// ---------------- weight transpose + split ----------------
// W [K, Nreal] fp32 row-major -> WT_hi/lo [Npad, K] bf16 row-major, zero-pad
__global__ void transpose_kernel(const float* __restrict__ W,
                                 __hip_bfloat16* __restrict__ WTh,
                                 __hip_bfloat16* __restrict__ WTl,
                                 int K, int Nreal, int Npad) {
  int idx = blockIdx.x * blockDim.x + threadIdx.x;
  if (idx >= Npad * K) return;
  int n = idx / K, k = idx - n * K;
  float v = (n < Nreal) ? sane(W[k * Nreal + n], 1e4f) : 0.f;
  __hip_bfloat16 h = f2bf(v);
  WTh[idx] = h;
  WTl[idx] = f2bf(v - bf2f(h));
}

// ---------------- GEMM: C = A @ W, split-bf16 inputs, fp32 acc --------------
// A given as hi/lo bf16 [M, KDIM]; WT as hi/lo [NOUT, KDIM] (transposed W).
// C written as hi/lo bf16 [M, NOUT].  D = Ah*Bh + Ah*Bl + Al*Bh (~fp16+ precision).
// A-frag: m=lane&15, k=quad*8+j.  B-frag: n=lane&15, k=quad*8+j.
// C/D: col=lane&15, row=quad*4+r.
template<int KDIM, int NOUT>
__global__ __launch_bounds__(256) void gemm_kernel(const __hip_bfloat16* __restrict__ Ah,
                                                   const __hip_bfloat16* __restrict__ Al,
                                                   const __hip_bfloat16* __restrict__ WTh,
                                                   const __hip_bfloat16* __restrict__ WTl,
                                                   __hip_bfloat16* __restrict__ Ch,
                                                   __hip_bfloat16* __restrict__ Cl,
                                                   int M) {
  constexpr int NT = NOUT / 16;
  int wave = threadIdx.x >> 6;
  int lane = threadIdx.x & 63;
  int row0 = blockIdx.x * 64 + wave * 16;
  if (row0 >= M) return;
  int m = lane & 15, quad = lane >> 4;
  size_t aoff = (size_t)(row0 + m) * KDIM + quad * 8;

  floatx4 acc[NT];
#pragma unroll
  for (int nt = 0; nt < NT; ++nt) acc[nt] = (floatx4){0.f, 0.f, 0.f, 0.f};

#pragma unroll
  for (int kk = 0; kk < KDIM; kk += 32) {
    short8 ah = *reinterpret_cast<const short8*>(Ah + aoff + kk);
    short8 al = *reinterpret_cast<const short8*>(Al + aoff + kk);
#pragma unroll
    for (int nt = 0; nt < NT; ++nt) {
      size_t boff = (size_t)(nt * 16 + m) * KDIM + kk + quad * 8;
      short8 bh = *reinterpret_cast<const short8*>(WTh + boff);
      short8 bl = *reinterpret_cast<const short8*>(WTl + boff);
      acc[nt] = __builtin_amdgcn_mfma_f32_16x16x32_bf16(ah, bh, acc[nt], 0, 0, 0);
      acc[nt] = __builtin_amdgcn_mfma_f32_16x16x32_bf16(ah, bl, acc[nt], 0, 0, 0);
      acc[nt] = __builtin_amdgcn_mfma_f32_16x16x32_bf16(al, bh, acc[nt], 0, 0, 0);
    }
  }
#pragma unroll
  for (int nt = 0; nt < NT; ++nt)
#pragma unroll
    for (int r = 0; r < 4; ++r) {
      float v = sane(acc[nt][r], 3e4f);  // distinct fingerprint clamp
      size_t o = (size_t)(row0 + quad * 4 + r) * NOUT + nt * 16 + m;
      __hip_bfloat16 h = f2bf(v);
      Ch[o] = h;
      Cl[o] = f2bf(v - bf2f(h));
    }
}

// ---------------- per-node attention logits (fp32 from hi+lo) ---------------
template<int H, int C, int FSTR>
__global__ __launch_bounds__(64) void attn_kernel(const __hip_bfloat16* __restrict__ Fh,
                                                  const __hip_bfloat16* __restrict__ Fl,
                                                  const float* __restrict__ a_s,
                                                  const float* __restrict__ a_d,
                                                  float* __restrict__ als,
                                                  float* __restrict__ ald) {
  constexpr int HC = H * C;
  constexpr int EPL = (HC + 63) / 64;  // elements per lane
  constexpr int G = 64 / H;            // lanes per head group
  int node = blockIdx.x;
  int lane = threadIdx.x;
  float ps = 0.f, pd = 0.f;
#pragma unroll
  for (int j = 0; j < EPL; ++j) {
    int idx = lane * EPL + j;
    if (idx < HC) {
      size_t o = (size_t)node * FSTR + idx;
      float f = bf2f(Fh[o]) + bf2f(Fl[o]);
      ps += f * sane(a_s[idx], 1e4f);
      pd += f * sane(a_d[idx], 1e4f);
    }
  }
#pragma unroll
  for (int off = G / 2; off > 0; off >>= 1) {
    ps += __shfl_down(ps, off, G);
    pd += __shfl_down(pd, off, G);
  }
  if ((lane & (G - 1)) == 0) {
    int head = lane / G;
    als[(size_t)node * H + head] = sane(ps, 80.f);
    ald[(size_t)node * H + head] = sane(pd, 80.f);
  }
}

// ---------------- softmax + aggregation over incoming edges ----------------
// Gathers hi-only bf16 feat (0.4% rel, fine). Mid layers write split hi/lo;
// final layer writes fp32 to d_out.
template<int H, int C, int FSTR, int OSTR, bool FINAL>
__global__ __launch_bounds__(256) void agg_kernel(const int* __restrict__ row_ptr,
                                                  const int* __restrict__ csr_src,
                                                  const __hip_bfloat16* __restrict__ Fh,
                                                  const float* __restrict__ als,
                                                  const float* __restrict__ ald,
                                                  const float* __restrict__ bias,
                                                  __hip_bfloat16* __restrict__ Oh,
                                                  __hip_bfloat16* __restrict__ Ol,
                                                  float* __restrict__ Of) {
  constexpr int T = H * C;
  constexpr int CAP = 256;
  __shared__ float w_s[CAP * H];
  __shared__ int s_src[CAP];
  __shared__ float denom[H];
  int dst = blockIdx.x;
  int t = threadIdx.x;
  int start = row_ptr[dst], end = row_ptr[dst + 1];
  if (t < H) denom[t] = 0.f;
  __syncthreads();
  int h = t / C;
  float acc = 0.f;
  bool have_edges = (end > start);
  if (have_edges) {
    for (int base = start; base < end; base += CAP) {
      int cnt = min(CAP, end - base);
      if (t < cnt) {
        int s = csr_src[base + t];
        s = min(max(s, 0), NNODES - 1);
        s_src[t] = s;
#pragma unroll
        for (int hh = 0; hh < H; ++hh) {
          float e = als[(size_t)s * H + hh] + ald[(size_t)dst * H + hh];
          e = e > 0.f ? e : 0.2f * e;                // LeakyReLU(0.2)
          e = fminf(fmaxf(e, -80.f), 80.f);
          float w = __expf(e);
          w_s[t * H + hh] = w;
          atomicAdd(&denom[hh], w);
        }
      }
      __syncthreads();
      if (t < T) {
        for (int p = 0; p < cnt; ++p)
          acc += w_s[p * H + h] * bf2f(Fh[(size_t)s_src[p] * FSTR + t]);
      }
      __syncthreads();
    }
  }
  if (t < T) {
    float b = sane(bias[t], 1e4f);
    float o = have_edges ? (acc / fmaxf(denom[h], 1e-30f) + b) : b;
    if (!FINAL) {
      o = o > 0.f ? o : __expf(o) - 1.f;             // ELU
      size_t idx = (size_t)dst * OSTR + t;
      __hip_bfloat16 hi = f2bf(o);
      Oh[idx] = hi;
      Ol[idx] = f2bf(o - bf2f(hi));
    } else {
      Of[(size_t)dst * OSTR + t] = o;
    }
  }
}

// ---------------- launch ----------------
extern "C" void kernel_launch(void* const* d_in, const int* in_sizes, int n_in,
                              void* d_out, int out_size, void* d_ws, size_t ws_size,
                              hipStream_t stream) {
  const float* x   = (const float*)d_in[0];
  const int* ei    = (const int*)d_in[1];
  const float* W1  = (const float*)d_in[2];
  const float* a1s = (const float*)d_in[3];
  const float* a1d = (const float*)d_in[4];
  const float* b1  = (const float*)d_in[5];
  const float* W2  = (const float*)d_in[6];
  const float* a2s = (const float*)d_in[7];
  const float* a2d = (const float*)d_in[8];
  const float* b2  = (const float*)d_in[9];
  const float* W3  = (const float*)d_in[10];
  const float* a3s = (const float*)d_in[11];
  const float* a3d = (const float*)d_in[12];
  const float* b3  = (const float*)d_in[13];
  float* out = (float*)d_out;
  (void)n_in; (void)in_sizes;

  // workspace layout
  char* base = (char*)d_ws;
  size_t off = 0;
  auto alloc = [&](size_t bytes) -> char* {
    off = (off + 255) & ~(size_t)255;
    char* p = base + off;
    off += bytes;
    return p;
  };
  int* deg     = (int*)alloc((size_t)NNODES * 4);
  int* cursor  = (int*)alloc((size_t)NNODES * 4);
  int* row_ptr = (int*)alloc((size_t)(NNODES + 1) * 4);
  int* csr_src = (int*)alloc((size_t)ETOT * 4);
  float* als   = (float*)alloc((size_t)NNODES * 4 * 4);
  float* ald   = (float*)alloc((size_t)NNODES * 4 * 4);
  __hip_bfloat16* Ah = (__hip_bfloat16*)alloc((size_t)NNODES * 256 * 2);  // GEMM input hi
  __hip_bfloat16* Al = (__hip_bfloat16*)alloc((size_t)NNODES * 256 * 2);  // GEMM input lo
  __hip_bfloat16* Fh = (__hip_bfloat16*)alloc((size_t)NNODES * 256 * 2);  // feat hi
  __hip_bfloat16* Fl = (__hip_bfloat16*)alloc((size_t)NNODES * 256 * 2);  // feat lo
  __hip_bfloat16* wth = (__hip_bfloat16*)alloc((size_t)256 * 256 * 2);
  __hip_bfloat16* wtl = (__hip_bfloat16*)alloc((size_t)256 * 256 * 2);

  // DIAGNOSTIC: if workspace too small, emit sentinel 12345
  if (ws_size < off) {
    fill_out_kernel<<<(out_size + 255) / 256, 256, 0, stream>>>(out, out_size, 12345.f);
    return;
  }

  // --- CSR build (shared by all 3 layers) ---
  zero_int_kernel<<<(NNODES + 255) / 256, 256, 0, stream>>>(deg, NNODES);
  degree_kernel<<<(ETOT + 255) / 256, 256, 0, stream>>>(ei, deg);
  scan_kernel<<<1, 256, 0, stream>>>(deg, row_ptr, cursor);
  scatter_kernel<<<(ETOT + 255) / 256, 256, 0, stream>>>(ei, cursor, csr_src);

  const int gemm_grid = (NNODES + 63) / 64;

  // split x (fp32 -> bf16 hi/lo), stride 128
  split_input_kernel<<<(NNODES * 128 + 255) / 256, 256, 0, stream>>>(x, Ah, Al, NNODES * 128);

  // --- layer 1: 128 -> 4x64, ELU ---
  transpose_kernel<<<(256 * 128 + 255) / 256, 256, 0, stream>>>(W1, wth, wtl, 128, 256, 256);
  gemm_kernel<128, 256><<<gemm_grid, 256, 0, stream>>>(Ah, Al, wth, wtl, Fh, Fl, NNODES);
  attn_kernel<4, 64, 256><<<NNODES, 64, 0, stream>>>(Fh, Fl, a1s, a1d, als, ald);
  agg_kernel<4, 64, 256, 256, false><<<NNODES, 256, 0, stream>>>(
      row_ptr, csr_src, Fh, als, ald, b1, Ah, Al, nullptr);

  // --- layer 2: 256 -> 4x64, ELU ---
  transpose_kernel<<<(256 * 256 + 255) / 256, 256, 0, stream>>>(W2, wth, wtl, 256, 256, 256);
  gemm_kernel<256, 256><<<gemm_grid, 256, 0, stream>>>(Ah, Al, wth, wtl, Fh, Fl, NNODES);
  attn_kernel<4, 64, 256><<<NNODES, 64, 0, stream>>>(Fh, Fl, a2s, a2d, als, ald);
  agg_kernel<4, 64, 256, 256, false><<<NNODES, 256, 0, stream>>>(
      row_ptr, csr_src, Fh, als, ald, b2, Ah, Al, nullptr);

  // --- layer 3: 256 -> 47 (padded to 64), no ELU, fp32 out ---
  transpose_kernel<<<(64 * 256 + 255) / 256, 256, 0, stream>>>(W3, wth, wtl, 256, 47, 64);
  gemm_kernel<256, 64><<<gemm_grid, 256, 0, stream>>>(Ah, Al, wth, wtl, Fh, Fl, NNODES);
  attn_kernel<1, 47, 64><<<NNODES, 64, 0, stream>>>(Fh, Fl, a3s, a3d, als, ald);
  agg_kernel<1, 47, 64, 47, true><<<NNODES, 256, 0, stream>>>(
      row_ptr, csr_src, Fh, als, ald, b3, nullptr, nullptr, out);
}

// Round 4
// 819.048 us; speedup vs baseline: 1.3040x; 1.3040x over previous
//
#include <hip/hip_runtime.h>
#include <hip/hip_bf16.h>

#define NNODES 50000
#define NEDGES 800000
#define ETOT   (NNODES + NEDGES)

typedef __attribute__((ext_vector_type(8))) short short8;
typedef __attribute__((ext_vector_type(4))) float floatx4;
typedef __attribute__((ext_vector_type(2))) unsigned int uint2v;

__device__ __forceinline__ float bf2f(__hip_bfloat16 x) { return __bfloat162float(x); }
__device__ __forceinline__ __hip_bfloat16 f2bf(float f) { return __float2bfloat16(f); }
__device__ __forceinline__ float sane(float v, float c) {
  v = (v == v) ? v : 0.f;
  return fminf(fmaxf(v, -c), c);
}

// ---------------- utility ----------------
__global__ void zero_int_kernel(int* __restrict__ p, int n) {
  int i = blockIdx.x * blockDim.x + threadIdx.x;
  if (i < n) p[i] = 0;
}
__global__ void fill_out_kernel(float* __restrict__ o, int n, float v) {
  int i = blockIdx.x * blockDim.x + threadIdx.x;
  if (i < n) o[i] = v;
}
__global__ void split_input_kernel(const float* __restrict__ in,
                                   __hip_bfloat16* __restrict__ hi,
                                   __hip_bfloat16* __restrict__ lo, int n) {
  int i = blockIdx.x * blockDim.x + threadIdx.x;
  if (i >= n) return;
  float v = sane(in[i], 1e4f);
  __hip_bfloat16 h = f2bf(v);
  hi[i] = h;
  lo[i] = f2bf(v - bf2f(h));
}
// pad 47-vec attention params to 64 with zeros
__global__ void pad47_kernel(const float* __restrict__ a, const float* __restrict__ b,
                             float* __restrict__ ap, float* __restrict__ bp) {
  int i = threadIdx.x;  // 64
  ap[i] = (i < 47) ? sane(a[i], 1e4f) : 0.f;
  bp[i] = (i < 47) ? sane(b[i], 1e4f) : 0.f;
}

// ---------------- CSR build (dst-sorted) ----------------
__global__ void degree_kernel(const int* __restrict__ ei, int* __restrict__ deg) {
  int p = blockIdx.x * blockDim.x + threadIdx.x;
  if (p >= ETOT) return;
  int dst = (p < NEDGES) ? ei[NEDGES + p] : (p - NEDGES);
  dst = min(max(dst, 0), NNODES - 1);
  atomicAdd(&deg[dst], 1);
}

__global__ __launch_bounds__(1024) void scan_kernel(const int* __restrict__ deg,
                                                    int* __restrict__ row_ptr,
                                                    int* __restrict__ cursor) {
  __shared__ int sh[1024];
  int t = threadIdx.x;
  const int n = NNODES;
  const int chunk = (n + 1023) / 1024;  // 49
  int beg = min(n, t * chunk);
  int end = min(n, beg + chunk);
  int s = 0;
  for (int i = beg; i < end; ++i) s += deg[i];
  sh[t] = s;
  __syncthreads();
  for (int off = 1; off < 1024; off <<= 1) {
    int v = (t >= off) ? sh[t - off] : 0;
    __syncthreads();
    sh[t] += v;
    __syncthreads();
  }
  int run = sh[t] - s;  // exclusive prefix
  for (int i = beg; i < end; ++i) {
    int d = deg[i];
    row_ptr[i] = run;
    cursor[i] = run;
    run += d;
  }
  if (t == 1023) row_ptr[n] = sh[1023];
}

__global__ void scatter_kernel(const int* __restrict__ ei, int* __restrict__ cursor,
                               int* __restrict__ csr_src) {
  int p = blockIdx.x * blockDim.x + threadIdx.x;
  if (p >= ETOT) return;
  int src, dst;
  if (p < NEDGES) { src = ei[p]; dst = ei[NEDGES + p]; }
  else            { src = p - NEDGES; dst = src; }
  src = min(max(src, 0), NNODES - 1);
  dst = min(max(dst, 0), NNODES - 1);
  int pos = atomicAdd(&cursor[dst], 1);
  pos = min(max(pos, 0), ETOT - 1);
  csr_src[pos] = src;
}

// ---------------- weight transpose + split ----------------
__global__ void transpose_kernel(const float* __restrict__ W,
                                 __hip_bfloat16* __restrict__ WTh,
                                 __hip_bfloat16* __restrict__ WTl,
                                 int K, int Nreal, int Npad) {
  int idx = blockIdx.x * blockDim.x + threadIdx.x;
  if (idx >= Npad * K) return;
  int n = idx / K, k = idx - n * K;
  float v = (n < Nreal) ? sane(W[k * Nreal + n], 1e4f) : 0.f;
  __hip_bfloat16 h = f2bf(v);
  WTh[idx] = h;
  WTl[idx] = f2bf(v - bf2f(h));
}

// ---------------- GEMM + fused attention logits ----------------
// C = A @ W (split-bf16, fp32 acc, 3 MFMAs), epilogue computes
// als[row,h] = feat_row . a_s[h], ald likewise, via xor-shuffle over m-lanes.
// A-frag: m=lane&15, k=quad*8+j. B-frag: n=lane&15, k=quad*8+j.
// C/D: col=lane&15, row=quad*4+r.
template<int KDIM, int NOUT, int HEADS>
__global__ __launch_bounds__(256) void gemm_attn_kernel(
    const __hip_bfloat16* __restrict__ Ah, const __hip_bfloat16* __restrict__ Al,
    const __hip_bfloat16* __restrict__ WTh, const __hip_bfloat16* __restrict__ WTl,
    const float* __restrict__ asv, const float* __restrict__ adv,
    __hip_bfloat16* __restrict__ Ch, float* __restrict__ als, float* __restrict__ ald,
    int M) {
  constexpr int NT = NOUT / 16;
  constexpr int TPH = NT / HEADS;  // MFMA col-tiles per head
  int wave = threadIdx.x >> 6;
  int lane = threadIdx.x & 63;
  int row0 = blockIdx.x * 64 + wave * 16;
  if (row0 >= M) return;
  int m = lane & 15, quad = lane >> 4;
  size_t aoff = (size_t)(row0 + m) * KDIM + quad * 8;

  floatx4 acc[NT];
#pragma unroll
  for (int nt = 0; nt < NT; ++nt) acc[nt] = (floatx4){0.f, 0.f, 0.f, 0.f};

#pragma unroll
  for (int kk = 0; kk < KDIM; kk += 32) {
    short8 ah = *reinterpret_cast<const short8*>(Ah + aoff + kk);
    short8 al = *reinterpret_cast<const short8*>(Al + aoff + kk);
#pragma unroll
    for (int nt = 0; nt < NT; ++nt) {
      size_t boff = (size_t)(nt * 16 + m) * KDIM + kk + quad * 8;
      short8 bh = *reinterpret_cast<const short8*>(WTh + boff);
      short8 bl = *reinterpret_cast<const short8*>(WTl + boff);
      acc[nt] = __builtin_amdgcn_mfma_f32_16x16x32_bf16(ah, bh, acc[nt], 0, 0, 0);
      acc[nt] = __builtin_amdgcn_mfma_f32_16x16x32_bf16(ah, bl, acc[nt], 0, 0, 0);
      acc[nt] = __builtin_amdgcn_mfma_f32_16x16x32_bf16(al, bh, acc[nt], 0, 0, 0);
    }
  }

  // fused attention logits
  float asl[NT], adl[NT];
#pragma unroll
  for (int nt = 0; nt < NT; ++nt) {
    asl[nt] = asv[nt * 16 + m];
    adl[nt] = adv[nt * 16 + m];
  }
  float ps[4 * HEADS], pd[4 * HEADS];
#pragma unroll
  for (int i = 0; i < 4 * HEADS; ++i) { ps[i] = 0.f; pd[i] = 0.f; }
#pragma unroll
  for (int nt = 0; nt < NT; ++nt) {
    int h = nt / TPH;
#pragma unroll
    for (int r = 0; r < 4; ++r) {
      ps[r * HEADS + h] += acc[nt][r] * asl[nt];
      pd[r * HEADS + h] += acc[nt][r] * adl[nt];
    }
  }
#pragma unroll
  for (int off = 1; off < 16; off <<= 1) {
#pragma unroll
    for (int i = 0; i < 4 * HEADS; ++i) {
      ps[i] += __shfl_xor(ps[i], off);
      pd[i] += __shfl_xor(pd[i], off);
    }
  }
  if (m == 0) {
#pragma unroll
    for (int r = 0; r < 4; ++r)
#pragma unroll
      for (int h = 0; h < HEADS; ++h) {
        int row = row0 + quad * 4 + r;
        als[(size_t)row * HEADS + h] = sane(ps[r * HEADS + h], 80.f);
        ald[(size_t)row * HEADS + h] = sane(pd[r * HEADS + h], 80.f);
      }
  }

  // store C (hi-only bf16)
#pragma unroll
  for (int nt = 0; nt < NT; ++nt)
#pragma unroll
    for (int r = 0; r < 4; ++r) {
      float v = sane(acc[nt][r], 3e4f);
      Ch[(size_t)(row0 + quad * 4 + r) * NOUT + nt * 16 + m] = f2bf(v);
    }
}

// ---------------- normalized edge weights (alpha) ----------------
// one wave per dst node; lane-per-edge; shuffle-reduce denominators
template<int H>
__global__ __launch_bounds__(256) void alpha_kernel(const int* __restrict__ row_ptr,
                                                    const int* __restrict__ csr_src,
                                                    const float* __restrict__ als,
                                                    const float* __restrict__ ald,
                                                    float* __restrict__ alpha) {
  int wid = threadIdx.x >> 6, lane = threadIdx.x & 63;
  int dst = blockIdx.x * 4 + wid;
  if (dst >= NNODES) return;
  int start = row_ptr[dst], end = row_ptr[dst + 1];
  int cnt = end - start;
  if (cnt <= 0) return;
  float adv[H];
#pragma unroll
  for (int h = 0; h < H; ++h) adv[h] = ald[(size_t)dst * H + h];

  if (cnt <= 64) {
    int i = start + lane;
    bool valid = lane < cnt;
    int s = valid ? min(max(csr_src[i], 0), NNODES - 1) : 0;
    float w[H];
#pragma unroll
    for (int h = 0; h < H; ++h) {
      float e = als[(size_t)s * H + h] + adv[h];
      e = e > 0.f ? e : 0.2f * e;
      e = fminf(fmaxf(e, -80.f), 80.f);
      w[h] = valid ? __expf(e) : 0.f;
    }
#pragma unroll
    for (int h = 0; h < H; ++h) {
      float v = w[h];
#pragma unroll
      for (int off = 1; off < 64; off <<= 1) v += __shfl_xor(v, off);
      float inv = 1.f / fmaxf(v, 1e-30f);
      if (valid) alpha[(size_t)i * H + h] = w[h] * inv;
    }
  } else {
    float dl[H];
#pragma unroll
    for (int h = 0; h < H; ++h) dl[h] = 0.f;
    for (int base = start; base < end; base += 64) {
      int i = base + lane;
      bool valid = i < end;
      int s = valid ? min(max(csr_src[i], 0), NNODES - 1) : 0;
#pragma unroll
      for (int h = 0; h < H; ++h) {
        float e = als[(size_t)s * H + h] + adv[h];
        e = e > 0.f ? e : 0.2f * e;
        e = fminf(fmaxf(e, -80.f), 80.f);
        float w = valid ? __expf(e) : 0.f;
        dl[h] += w;
        if (valid) alpha[(size_t)i * H + h] = w;
      }
    }
    float inv[H];
#pragma unroll
    for (int h = 0; h < H; ++h) {
      float v = dl[h];
#pragma unroll
      for (int off = 1; off < 64; off <<= 1) v += __shfl_xor(v, off);
      inv[h] = 1.f / fmaxf(v, 1e-30f);
    }
    for (int base = start; base < end; base += 64) {
      int i = base + lane;
      if (i < end)
#pragma unroll
        for (int h = 0; h < H; ++h) alpha[(size_t)i * H + h] *= inv[h];
    }
  }
}

// ---------------- aggregation, mid layers (T=256, H=4) ----------------
// block = 4 waves per dst; lane owns 4 cols (one dwordx2 bf16x4 load);
// waves stride edges; LDS cross-wave reduce; ELU + hi/lo split epilogue.
__global__ __launch_bounds__(256) void agg_mid_kernel(const int* __restrict__ row_ptr,
                                                      const int* __restrict__ csr_src,
                                                      const __hip_bfloat16* __restrict__ Fh,
                                                      const float* __restrict__ alpha,
                                                      const float* __restrict__ bias,
                                                      __hip_bfloat16* __restrict__ Oh,
                                                      __hip_bfloat16* __restrict__ Ol) {
  __shared__ float part[4][256];
  int dst = blockIdx.x;
  int wid = threadIdx.x >> 6, lane = threadIdx.x & 63;
  int start = row_ptr[dst], end = row_ptr[dst + 1];
  int cnt = end - start;
  int head = lane >> 4;
  float a0 = 0.f, a1 = 0.f, a2 = 0.f, a3 = 0.f;
  int p = wid;
  for (; p + 4 < cnt; p += 8) {  // 2 edges in flight per wave
    int e0 = start + p, e1 = start + p + 4;
    int s0 = csr_src[e0], s1 = csr_src[e1];
    float w0 = alpha[(size_t)e0 * 4 + head];
    float w1 = alpha[(size_t)e1 * 4 + head];
    uint2v f0 = *reinterpret_cast<const uint2v*>(Fh + (size_t)s0 * 256 + lane * 4);
    uint2v f1 = *reinterpret_cast<const uint2v*>(Fh + (size_t)s1 * 256 + lane * 4);
    a0 += w0 * __uint_as_float(f0.x << 16);
    a1 += w0 * __uint_as_float(f0.x & 0xffff0000u);
    a2 += w0 * __uint_as_float(f0.y << 16);
    a3 += w0 * __uint_as_float(f0.y & 0xffff0000u);
    a0 += w1 * __uint_as_float(f1.x << 16);
    a1 += w1 * __uint_as_float(f1.x & 0xffff0000u);
    a2 += w1 * __uint_as_float(f1.y << 16);
    a3 += w1 * __uint_as_float(f1.y & 0xffff0000u);
  }
  for (; p < cnt; p += 4) {
    int e0 = start + p;
    int s0 = csr_src[e0];
    float w0 = alpha[(size_t)e0 * 4 + head];
    uint2v f0 = *reinterpret_cast<const uint2v*>(Fh + (size_t)s0 * 256 + lane * 4);
    a0 += w0 * __uint_as_float(f0.x << 16);
    a1 += w0 * __uint_as_float(f0.x & 0xffff0000u);
    a2 += w0 * __uint_as_float(f0.y << 16);
    a3 += w0 * __uint_as_float(f0.y & 0xffff0000u);
  }
  *reinterpret_cast<floatx4*>(&part[wid][lane * 4]) = (floatx4){a0, a1, a2, a3};
  __syncthreads();
  int t = threadIdx.x;
  float o = part[0][t] + part[1][t] + part[2][t] + part[3][t] + bias[t];
  o = o > 0.f ? o : __expf(o) - 1.f;  // ELU
  __hip_bfloat16 h = f2bf(o);
  Oh[(size_t)dst * 256 + t] = h;
  Ol[(size_t)dst * 256 + t] = f2bf(o - bf2f(h));
}

// ---------------- aggregation, final layer (64-pad feat, 47 out, fp32) ------
__global__ __launch_bounds__(256) void agg_final_kernel(const int* __restrict__ row_ptr,
                                                        const int* __restrict__ csr_src,
                                                        const __hip_bfloat16* __restrict__ Fh,
                                                        const float* __restrict__ alpha,
                                                        const float* __restrict__ bias,
                                                        float* __restrict__ out) {
  int wid = threadIdx.x >> 6, lane = threadIdx.x & 63;
  int dst = blockIdx.x * 4 + wid;
  if (dst >= NNODES) return;
  int start = row_ptr[dst], end = row_ptr[dst + 1];
  float acc = 0.f;
  int e = start;
  for (; e + 1 < end; e += 2) {
    int s0 = csr_src[e], s1 = csr_src[e + 1];
    float w0 = alpha[e], w1 = alpha[e + 1];
    float f0 = bf2f(Fh[(size_t)s0 * 64 + lane]);
    float f1 = bf2f(Fh[(size_t)s1 * 64 + lane]);
    acc += w0 * f0 + w1 * f1;
  }
  for (; e < end; ++e) {
    int s0 = csr_src[e];
    acc += alpha[e] * bf2f(Fh[(size_t)s0 * 64 + lane]);
  }
  if (lane < 47) out[(size_t)dst * 47 + lane] = acc + bias[lane];
}

// ---------------- launch ----------------
extern "C" void kernel_launch(void* const* d_in, const int* in_sizes, int n_in,
                              void* d_out, int out_size, void* d_ws, size_t ws_size,
                              hipStream_t stream) {
  const float* x   = (const float*)d_in[0];
  const int* ei    = (const int*)d_in[1];
  const float* W1  = (const float*)d_in[2];
  const float* a1s = (const float*)d_in[3];
  const float* a1d = (const float*)d_in[4];
  const float* b1  = (const float*)d_in[5];
  const float* W2  = (const float*)d_in[6];
  const float* a2s = (const float*)d_in[7];
  const float* a2d = (const float*)d_in[8];
  const float* b2  = (const float*)d_in[9];
  const float* W3  = (const float*)d_in[10];
  const float* a3s = (const float*)d_in[11];
  const float* a3d = (const float*)d_in[12];
  const float* b3  = (const float*)d_in[13];
  float* out = (float*)d_out;
  (void)n_in; (void)in_sizes;

  char* base = (char*)d_ws;
  size_t off = 0;
  auto alloc = [&](size_t bytes) -> char* {
    off = (off + 255) & ~(size_t)255;
    char* p = base + off;
    off += bytes;
    return p;
  };
  int* deg     = (int*)alloc((size_t)NNODES * 4);
  int* cursor  = (int*)alloc((size_t)NNODES * 4);
  int* row_ptr = (int*)alloc((size_t)(NNODES + 1) * 4);
  int* csr_src = (int*)alloc((size_t)ETOT * 4);
  float* als   = (float*)alloc((size_t)NNODES * 4 * 4);
  float* ald   = (float*)alloc((size_t)NNODES * 4 * 4);
  float* alpha = (float*)alloc((size_t)ETOT * 4 * 4);
  __hip_bfloat16* Ah = (__hip_bfloat16*)alloc((size_t)NNODES * 256 * 2);
  __hip_bfloat16* Al = (__hip_bfloat16*)alloc((size_t)NNODES * 256 * 2);
  __hip_bfloat16* Fh = (__hip_bfloat16*)alloc((size_t)NNODES * 256 * 2);
  __hip_bfloat16* wth = (__hip_bfloat16*)alloc((size_t)256 * 256 * 2);
  __hip_bfloat16* wtl = (__hip_bfloat16*)alloc((size_t)256 * 256 * 2);
  float* asv3 = (float*)alloc(64 * 4);
  float* adv3 = (float*)alloc(64 * 4);

  if (ws_size < off) {
    fill_out_kernel<<<(out_size + 255) / 256, 256, 0, stream>>>(out, out_size, 12345.f);
    return;
  }

  // CSR build (shared by all layers)
  zero_int_kernel<<<(NNODES + 255) / 256, 256, 0, stream>>>(deg, NNODES);
  degree_kernel<<<(ETOT + 255) / 256, 256, 0, stream>>>(ei, deg);
  scan_kernel<<<1, 1024, 0, stream>>>(deg, row_ptr, cursor);
  scatter_kernel<<<(ETOT + 255) / 256, 256, 0, stream>>>(ei, cursor, csr_src);

  const int gemm_grid = (NNODES + 63) / 64;
  split_input_kernel<<<(NNODES * 128 + 255) / 256, 256, 0, stream>>>(x, Ah, Al, NNODES * 128);
  pad47_kernel<<<1, 64, 0, stream>>>(a3s, a3d, asv3, adv3);

  // layer 1: 128 -> 4x64, ELU
  transpose_kernel<<<(256 * 128 + 255) / 256, 256, 0, stream>>>(W1, wth, wtl, 128, 256, 256);
  gemm_attn_kernel<128, 256, 4><<<gemm_grid, 256, 0, stream>>>(Ah, Al, wth, wtl, a1s, a1d,
                                                               Fh, als, ald, NNODES);
  alpha_kernel<4><<<(NNODES + 3) / 4, 256, 0, stream>>>(row_ptr, csr_src, als, ald, alpha);
  agg_mid_kernel<<<NNODES, 256, 0, stream>>>(row_ptr, csr_src, Fh, alpha, b1, Ah, Al);

  // layer 2: 256 -> 4x64, ELU
  transpose_kernel<<<(256 * 256 + 255) / 256, 256, 0, stream>>>(W2, wth, wtl, 256, 256, 256);
  gemm_attn_kernel<256, 256, 4><<<gemm_grid, 256, 0, stream>>>(Ah, Al, wth, wtl, a2s, a2d,
                                                               Fh, als, ald, NNODES);
  alpha_kernel<4><<<(NNODES + 3) / 4, 256, 0, stream>>>(row_ptr, csr_src, als, ald, alpha);
  agg_mid_kernel<<<NNODES, 256, 0, stream>>>(row_ptr, csr_src, Fh, alpha, b2, Ah, Al);

  // layer 3: 256 -> 47 (pad 64), no ELU, fp32 out
  transpose_kernel<<<(64 * 256 + 255) / 256, 256, 0, stream>>>(W3, wth, wtl, 256, 47, 64);
  gemm_attn_kernel<256, 64, 1><<<gemm_grid, 256, 0, stream>>>(Ah, Al, wth, wtl, asv3, adv3,
                                                              Fh, als, ald, NNODES);
  alpha_kernel<1><<<(NNODES + 3) / 4, 256, 0, stream>>>(row_ptr, csr_src, als, ald, alpha);
  agg_final_kernel<<<(NNODES + 3) / 4, 256, 0, stream>>>(row_ptr, csr_src, Fh, alpha, b3, out);
}